// Round 2
// baseline (433.381 us; speedup 1.0000x reference)
//
#include <hip/hip_runtime.h>
#include <hip/hip_bf16.h>

typedef __bf16 bf16;
typedef bf16 bf16x8 __attribute__((ext_vector_type(8)));
typedef float f32x4 __attribute__((ext_vector_type(4)));

#define MFMA16(a, b, c) __builtin_amdgcn_mfma_f32_16x16x32_bf16((a), (b), (c), 0, 0, 0)

// Problem constants
#define MM 3
#define AA 4
#define BB 2048
#define LL 7
#define HH 256
#define VN 50000

// ---------------------------------------------------------------------------
// prep: transpose+bf16 weights, cos/sin edge tables, zero S accumulator
// ---------------------------------------------------------------------------
__global__ void prep_kernel(const float* __restrict__ scale_W, const float* __restrict__ attn_W,
                            const float* __restrict__ inter_W, const float* __restrict__ out_W,
                            const float* __restrict__ edge_emb,
                            bf16* __restrict__ scale_WT, bf16* __restrict__ attn_WT,
                            bf16* __restrict__ inter_WT, bf16* __restrict__ out_WT,
                            float* __restrict__ ce, float* __restrict__ se,
                            float* __restrict__ S) {
    int idx = blockIdx.x * blockDim.x + threadIdx.x;
    int stride = gridDim.x * blockDim.x;
    for (int i = idx; i < 256 * 256; i += stride) {
        int k = i >> 8, c = i & 255;
        scale_WT[c * 256 + k] = (bf16)scale_W[i];
    }
    for (int i = idx; i < 512 * 512; i += stride) {
        int k = i >> 9, c = i & 511;
        attn_WT[c * 512 + k] = (bf16)attn_W[i];
    }
    for (int i = idx; i < 512 * 512; i += stride) {
        int k = i >> 9, c = i & 511;
        inter_WT[c * 512 + k] = (bf16)inter_W[i];
    }
    for (int i = idx; i < 512 * 256; i += stride) {
        int k = i >> 8, c = i & 255;
        out_WT[c * 512 + k] = (bf16)out_W[i];
    }
    for (int i = idx; i < 16 * 128; i += stride) {
        float e = edge_emb[i];
        ce[i] = cosf(e);
        se[i] = sinf(e);
    }
    for (int i = idx; i < 3 * 512; i += stride) S[i] = 0.f;
}

// ---------------------------------------------------------------------------
// K1: scaled_emb[v] = node_emb[v] @ scale_W + scale_b   (bf16 out)
// block: 128 rows x 256 cols, K=256. 512 threads / 8 waves.
// ---------------------------------------------------------------------------
__global__ __launch_bounds__(512) void emb_gemm_kernel(
    const float* __restrict__ node_emb, const bf16* __restrict__ scale_WT,
    const float* __restrict__ scale_b, bf16* __restrict__ scaled_emb) {
    extern __shared__ char smem[];
    bf16* Al = (bf16*)smem;                    // [128][264]
    bf16* Wl = (bf16*)(smem + 128 * 264 * 2);  // [128][72]
    const int tid = threadIdx.x;
    const int vb = blockIdx.x * 128;

    for (int i = tid; i < 128 * 64; i += 512) {
        int r = i >> 6, kq = i & 63;
        int v = vb + r;
        float4 x = (v < VN) ? *(const float4*)(node_emb + (size_t)v * 256 + kq * 4)
                            : make_float4(0.f, 0.f, 0.f, 0.f);
        bf16* d = Al + r * 264 + kq * 4;
        d[0] = (bf16)x.x; d[1] = (bf16)x.y; d[2] = (bf16)x.z; d[3] = (bf16)x.w;
    }
    const int w = tid >> 6, l = tid & 63, lr = l & 15, g = l >> 4;
    for (int cc = 0; cc < 2; ++cc) {
        f32x4 acc[8] = {};
        for (int kc = 0; kc < 4; ++kc) {
            __syncthreads();
            for (int i = tid; i < 128 * 8; i += 512) {
                int c = i >> 3, s = i & 7;
                *(bf16x8*)(Wl + c * 72 + s * 8) =
                    *(const bf16x8*)(scale_WT + (cc * 128 + c) * 256 + kc * 64 + s * 8);
            }
            __syncthreads();
#pragma unroll
            for (int kk = 0; kk < 2; ++kk) {
                bf16x8 aF = *(const bf16x8*)(Al + (w * 16 + lr) * 264 + kc * 64 + kk * 32 + g * 8);
#pragma unroll
                for (int ct = 0; ct < 8; ++ct) {
                    bf16x8 bF = *(const bf16x8*)(Wl + (ct * 16 + lr) * 72 + kk * 32 + g * 8);
                    acc[ct] = MFMA16(aF, bF, acc[ct]);
                }
            }
        }
#pragma unroll
        for (int ct = 0; ct < 8; ++ct) {
            int col = cc * 128 + ct * 16 + lr;
            float bia = scale_b[col];
#pragma unroll
            for (int i2 = 0; i2 < 4; ++i2) {
                int v = vb + w * 16 + g * 4 + i2;
                if (v < VN) scaled_emb[(size_t)v * 256 + col] = (bf16)(acc[ct][i2] + bia);
            }
        }
    }
}

// ---------------------------------------------------------------------------
// K3: fused gather + rotational scan + split attn GEMM + logits + softmax +
//     weighted sum + A-reduction -> hid[b][m][512]
// block: (m, bgroup of 4 b's) -> 16 n-instances (4 a x 4 b), 512 threads.
// LDS rows indexed AROW(q,p) = (p*16+q)*264, q = a*4 + bi.
// ---------------------------------------------------------------------------
#define AROW(q, p) (((p) * 16 + (q)) * 264)

__global__ __launch_bounds__(512) void metapath_kernel(
    const int* __restrict__ tokens, const int* __restrict__ etok,
    const bf16* __restrict__ scaled_emb, const bf16* __restrict__ attn_WT,
    const float* __restrict__ attn_b, const float* __restrict__ ctx,
    const float* __restrict__ ce, const float* __restrict__ se,
    float* __restrict__ hid) {
    extern __shared__ char smem[];
    bf16* Al = (bf16*)smem;                              // [8][16][264] = 67584 B
    bf16* Wl = (bf16*)(smem + 67584);                    // [2][128][72] = 36864 B
    float* y0 = (float*)(smem + 67584 + 36864);          // [16][132]    = 8448 B
    float* lg = (float*)(smem + 67584 + 36864 + 8448);   // [16][8]
    float* wsm = lg + 128;                               // [16][8]
    const int tid = threadIdx.x;
    const int m = blockIdx.y, bg = blockIdx.x;

    // 1. gather scaled_emb rows for 16 n's x 8 positions
    for (int i = tid; i < 128 * 32; i += 512) {
        int row = i >> 5, s = i & 31;
        int q = row & 15, p = row >> 4;
        int a = q >> 2, b = bg * 4 + (q & 3);
        int v = tokens[(((m * AA + a) * BB + b) << 3) + p];
        *(bf16x8*)(Al + row * 264 + s * 8) = *(const bf16x8*)(scaled_emb + (size_t)v * 256 + s * 8);
    }
    __syncthreads();

    // 2. in-place rotational-encoding scan (h_j = sum_{k<=j} P_k * x_k / (j+1))
    for (int i = tid; i < 2048; i += 512) {
        int q = i >> 7, c = i & 127;
        int a = q >> 2, b = bg * 4 + (q & 3);
        const int* eb = etok + ((m * AA + a) * BB + b) * LL;
        float Sr = (float)Al[AROW(q, 0) + c];
        float Si = (float)Al[AROW(q, 0) + c + 128];
        float Pr = 1.f, Pi = 0.f;
#pragma unroll
        for (int k = 1; k <= LL; ++k) {
            int e = eb[k - 1];
            float cr = ce[e * 128 + c], ci = se[e * 128 + c];
            float nPr = Pr * cr - Pi * ci;
            float nPi = Pr * ci + Pi * cr;
            Pr = nPr; Pi = nPi;
            float xr = (float)Al[AROW(q, k) + c];
            float xi = (float)Al[AROW(q, k) + c + 128];
            Sr += Pr * xr - Pi * xi;
            Si += Pr * xi + Pi * xr;
            float inv = 1.f / (float)(k + 1);
            Al[AROW(q, k) + c] = (bf16)(Sr * inv);
            Al[AROW(q, k) + c + 128] = (bf16)(Si * inv);
        }
    }
    __syncthreads();

    // 3. GEMM: waves 0..6 -> y1 = h_{w+1} . W_bot ; wave 7 -> y0 = h0 . W_top
    const int w = tid >> 6, l = tid & 63, lr = l & 15, g = l >> 4;
    const int p = (w == 7) ? 0 : (w + 1);
    float lp[4] = {0.f, 0.f, 0.f, 0.f};
    for (int cc = 0; cc < 4; ++cc) {
        f32x4 acc[8] = {};
        for (int kc = 0; kc < 4; ++kc) {
            __syncthreads();
            for (int i = tid; i < 2048; i += 512) {
                int t = i >> 10, rem = i & 1023, c = rem >> 3, s = rem & 7;
                *(bf16x8*)(Wl + t * 9216 + c * 72 + s * 8) =
                    *(const bf16x8*)(attn_WT + (cc * 128 + c) * 512 + t * 256 + kc * 64 + s * 8);
            }
            __syncthreads();
#pragma unroll
            for (int kk = 0; kk < 2; ++kk) {
                bf16x8 aF = *(const bf16x8*)(Al + AROW(lr, p) + kc * 64 + kk * 32 + g * 8);
                const bf16* wb = Wl + (w == 7 ? 0 : 9216);
#pragma unroll
                for (int ct = 0; ct < 8; ++ct) {
                    bf16x8 bF = *(const bf16x8*)(wb + (ct * 16 + lr) * 72 + kk * 32 + g * 8);
                    acc[ct] = MFMA16(aF, bF, acc[ct]);
                }
            }
        }
        __syncthreads();
        if (w == 7) {
#pragma unroll
            for (int ct = 0; ct < 8; ++ct) {
                int c = ct * 16 + lr;
#pragma unroll
                for (int i2 = 0; i2 < 4; ++i2) y0[(g * 4 + i2) * 132 + c] = acc[ct][i2];
            }
        }
        __syncthreads();
        if (w < 7) {
#pragma unroll
            for (int ct = 0; ct < 8; ++ct) {
                int c = ct * 16 + lr, cg = cc * 128 + c;
                float bia = attn_b[cg], cx = ctx[cg];
#pragma unroll
                for (int i2 = 0; i2 < 4; ++i2) {
                    float z = acc[ct][i2] + y0[(g * 4 + i2) * 132 + c] + bia;
                    lp[i2] += cx * tanhf(z);
                }
            }
        }
    }
    // reduce logit partials over the 16 column-lanes
#pragma unroll
    for (int msk = 1; msk < 16; msk <<= 1)
#pragma unroll
        for (int i2 = 0; i2 < 4; ++i2) lp[i2] += __shfl_xor(lp[i2], msk, 64);
    if (w < 7 && lr == 0) {
#pragma unroll
        for (int i2 = 0; i2 < 4; ++i2) lg[(g * 4 + i2) * 8 + w] = lp[i2];
    }
    __syncthreads();

    // 4. softmax over 7 positions (one thread per q)
    if (tid < 16) {
        int q = tid;
        float mx = -1e30f;
        for (int j = 0; j < LL; ++j) mx = fmaxf(mx, lg[q * 8 + j]);
        float ev[LL], ssum = 0.f;
        for (int j = 0; j < LL; ++j) { ev[j] = expf(lg[q * 8 + j] - mx); ssum += ev[j]; }
        float inv = 1.f / ssum;
        for (int j = 0; j < LL; ++j) wsm[q * 8 + j] = ev[j] * inv;
    }
    __syncthreads();

    // 5. weighted sum + relu + sum over a -> hid[b][m][c]
    for (int i = tid; i < 2048; i += 512) {
        int bi = i >> 9, c = i & 511;
        float accv = 0.f;
#pragma unroll
        for (int a = 0; a < AA; ++a) {
            int q = a * 4 + bi;
            if (c < 256) {
                accv += fmaxf(0.f, (float)Al[AROW(q, 0) + c]);
            } else {
                float s = 0.f;
#pragma unroll
                for (int j = 0; j < LL; ++j)
                    s += wsm[q * 8 + j] * (float)Al[AROW(q, j + 1) + (c - 256)];
                accv += fmaxf(0.f, s);
            }
        }
        hid[((size_t)(bg * 4 + bi) * 3 + m) * 512 + c] = accv;
    }
}

// ---------------------------------------------------------------------------
// K4a: S[m][c] += sum_b tanh(hid[b][m] . inter_W[:,c] + inter_b[c])
// grid (32 row-blocks, 3 m), 64 rows/block, K=512.
// ---------------------------------------------------------------------------
__global__ __launch_bounds__(512) void inter_kernel(
    const float* __restrict__ hid, const bf16* __restrict__ inter_WT,
    const float* __restrict__ inter_b, float* __restrict__ S) {
    extern __shared__ char smem[];
    bf16* Al = (bf16*)smem;                   // [64][520]
    bf16* Wl = (bf16*)(smem + 64 * 520 * 2);  // [128][72]
    const int tid = threadIdx.x;
    const int m = blockIdx.y, rb = blockIdx.x * 64;
    for (int i = tid; i < 64 * 128; i += 512) {
        int r = i >> 7, kq = i & 127;
        float4 x = *(const float4*)(hid + ((size_t)(rb + r) * 3 + m) * 512 + kq * 4);
        bf16* d = Al + r * 520 + kq * 4;
        d[0] = (bf16)x.x; d[1] = (bf16)x.y; d[2] = (bf16)x.z; d[3] = (bf16)x.w;
    }
    const int w = tid >> 6, l = tid & 63, lr = l & 15, g = l >> 4;
    const int rt = w >> 1, ch = w & 1;
    for (int cc = 0; cc < 4; ++cc) {
        f32x4 acc[4] = {};
        for (int kc = 0; kc < 8; ++kc) {
            __syncthreads();
            for (int i = tid; i < 1024; i += 512) {
                int c = i >> 3, s = i & 7;
                *(bf16x8*)(Wl + c * 72 + s * 8) =
                    *(const bf16x8*)(inter_WT + (cc * 128 + c) * 512 + kc * 64 + s * 8);
            }
            __syncthreads();
#pragma unroll
            for (int kk = 0; kk < 2; ++kk) {
                bf16x8 aF = *(const bf16x8*)(Al + (rt * 16 + lr) * 520 + kc * 64 + kk * 32 + g * 8);
#pragma unroll
                for (int t = 0; t < 4; ++t) {
                    bf16x8 bF = *(const bf16x8*)(Wl + ((ch * 4 + t) * 16 + lr) * 72 + kk * 32 + g * 8);
                    acc[t] = MFMA16(aF, bF, acc[t]);
                }
            }
        }
#pragma unroll
        for (int t = 0; t < 4; ++t) {
            int cg = cc * 128 + (ch * 4 + t) * 16 + lr;
            float bia = inter_b[cg];
            float sum = 0.f;
#pragma unroll
            for (int i2 = 0; i2 < 4; ++i2) sum += tanhf(acc[t][i2] + bia);
            sum += __shfl_xor(sum, 16, 64);
            sum += __shfl_xor(sum, 32, 64);
            if (g == 0) atomicAdd(&S[m * 512 + cg], sum);
        }
    }
}

// ---------------------------------------------------------------------------
// K4b: scores[m] = (sum_c S[m][c] * inter_context[c]) / 2048
// ---------------------------------------------------------------------------
__global__ void scores_kernel(const float* __restrict__ S, const float* __restrict__ ictx2,
                              float* __restrict__ scores) {
    __shared__ float red[512];
    int t = threadIdx.x;
    for (int m = 0; m < 3; ++m) {
        red[t] = S[m * 512 + t] * ictx2[t];
        __syncthreads();
        for (int st = 256; st > 0; st >>= 1) {
            if (t < st) red[t] += red[t + st];
            __syncthreads();
        }
        if (t == 0) scores[m] = red[0] * (1.f / 2048.f);
        __syncthreads();
    }
}

// ---------------------------------------------------------------------------
// K4c: out[b] = (sum_m hid[b][m] * scores[m]) @ out_W + out_b
// ---------------------------------------------------------------------------
__global__ __launch_bounds__(512) void out_kernel(
    const float* __restrict__ hid, const float* __restrict__ scores,
    const bf16* __restrict__ out_WT, const float* __restrict__ out_b,
    float* __restrict__ out) {
    extern __shared__ char smem[];
    bf16* Al = (bf16*)smem;                   // [64][520]
    bf16* Wl = (bf16*)(smem + 64 * 520 * 2);  // [128][72]
    const int tid = threadIdx.x;
    const int rb = blockIdx.x * 64;
    float s0 = scores[0], s1 = scores[1], s2 = scores[2];
    for (int i = tid; i < 64 * 128; i += 512) {
        int r = i >> 7, kq = i & 127;
        const float* hp = hid + (size_t)(rb + r) * 1536 + kq * 4;
        float4 x0 = *(const float4*)(hp);
        float4 x1 = *(const float4*)(hp + 512);
        float4 x2 = *(const float4*)(hp + 1024);
        bf16* d = Al + r * 520 + kq * 4;
        d[0] = (bf16)(x0.x * s0 + x1.x * s1 + x2.x * s2);
        d[1] = (bf16)(x0.y * s0 + x1.y * s1 + x2.y * s2);
        d[2] = (bf16)(x0.z * s0 + x1.z * s1 + x2.z * s2);
        d[3] = (bf16)(x0.w * s0 + x1.w * s1 + x2.w * s2);
    }
    const int w = tid >> 6, l = tid & 63, lr = l & 15, g = l >> 4;
    const int rt = w >> 1, ch = w & 1;
    for (int cc = 0; cc < 2; ++cc) {
        f32x4 acc[4] = {};
        for (int kc = 0; kc < 8; ++kc) {
            __syncthreads();
            for (int i = tid; i < 1024; i += 512) {
                int c = i >> 3, s = i & 7;
                *(bf16x8*)(Wl + c * 72 + s * 8) =
                    *(const bf16x8*)(out_WT + (cc * 128 + c) * 512 + kc * 64 + s * 8);
            }
            __syncthreads();
#pragma unroll
            for (int kk = 0; kk < 2; ++kk) {
                bf16x8 aF = *(const bf16x8*)(Al + (rt * 16 + lr) * 520 + kc * 64 + kk * 32 + g * 8);
#pragma unroll
                for (int t = 0; t < 4; ++t) {
                    bf16x8 bF = *(const bf16x8*)(Wl + ((ch * 4 + t) * 16 + lr) * 72 + kk * 32 + g * 8);
                    acc[t] = MFMA16(aF, bF, acc[t]);
                }
            }
        }
#pragma unroll
        for (int t = 0; t < 4; ++t) {
            int cg = cc * 128 + (ch * 4 + t) * 16 + lr;
            float bia = out_b[cg];
#pragma unroll
            for (int i2 = 0; i2 < 4; ++i2) {
                int b = rb + rt * 16 + g * 4 + i2;
                out[(size_t)b * 256 + cg] = acc[t][i2] + bia;
            }
        }
    }
}

// ---------------------------------------------------------------------------
extern "C" void kernel_launch(void* const* d_in, const int* in_sizes, int n_in,
                              void* d_out, int out_size, void* d_ws, size_t ws_size,
                              hipStream_t stream) {
    const int* tokens = (const int*)d_in[0];
    const int* etok = (const int*)d_in[1];
    const float* node_emb = (const float*)d_in[2];
    const float* edge_emb = (const float*)d_in[3];
    const float* scale_W = (const float*)d_in[4];
    const float* scale_b = (const float*)d_in[5];
    const float* attn_W = (const float*)d_in[6];
    const float* attn_b = (const float*)d_in[7];
    const float* ictx = (const float*)d_in[8];
    const float* inter_W = (const float*)d_in[9];
    const float* inter_b = (const float*)d_in[10];
    const float* ictx2 = (const float*)d_in[11];
    const float* out_W = (const float*)d_in[12];
    const float* out_b = (const float*)d_in[13];
    float* out = (float*)d_out;
    char* ws = (char*)d_ws;

    // ws layout (bytes)
    size_t off = 0;
    bf16* scale_WT = (bf16*)(ws + off); off += 256 * 256 * 2;       // 131072
    bf16* attn_WT = (bf16*)(ws + off);  off += 512 * 512 * 2;       // 524288
    bf16* inter_WT = (bf16*)(ws + off); off += 512 * 512 * 2;       // 524288
    bf16* out_WT = (bf16*)(ws + off);   off += 512 * 256 * 2;       // 262144
    float* ce = (float*)(ws + off);     off += 16 * 128 * 4;        // 8192
    float* se = (float*)(ws + off);     off += 16 * 128 * 4;        // 8192
    float* S = (float*)(ws + off);      off += 3 * 512 * 4;         // 6144
    float* scores = (float*)(ws + off); off += 256;
    bf16* scaled_emb = (bf16*)(ws + off); off += (size_t)VN * 256 * 2;   // 25.6 MB
    float* hid = (float*)(ws + off);    off += (size_t)BB * 3 * 512 * 4; // 12.6 MB
    if (ws_size < off) return;  // insufficient scratch -> fail loudly (zeros)

    const int lds_k1 = 128 * 264 * 2 + 128 * 72 * 2;                 // 86016
    const int lds_k3 = 67584 + 36864 + 8448 + 1024;                  // 113920
    const int lds_k4 = 64 * 520 * 2 + 128 * 72 * 2;                  // 84992
    // allow >64KB dynamic LDS (no-op if already allowed)
    (void)hipFuncSetAttribute((const void*)emb_gemm_kernel,
                              hipFuncAttributeMaxDynamicSharedMemorySize, lds_k1);
    (void)hipFuncSetAttribute((const void*)metapath_kernel,
                              hipFuncAttributeMaxDynamicSharedMemorySize, lds_k3);
    (void)hipFuncSetAttribute((const void*)inter_kernel,
                              hipFuncAttributeMaxDynamicSharedMemorySize, lds_k4);
    (void)hipFuncSetAttribute((const void*)out_kernel,
                              hipFuncAttributeMaxDynamicSharedMemorySize, lds_k4);

    prep_kernel<<<1024, 256, 0, stream>>>(scale_W, attn_W, inter_W, out_W, edge_emb,
                                          scale_WT, attn_WT, inter_WT, out_WT, ce, se, S);
    emb_gemm_kernel<<<(VN + 127) / 128, 512, lds_k1, stream>>>(node_emb, scale_WT, scale_b,
                                                               scaled_emb);
    metapath_kernel<<<dim3(BB / 4, MM), 512, lds_k3, stream>>>(tokens, etok, scaled_emb,
                                                               attn_WT, attn_b, ictx, ce, se, hid);
    inter_kernel<<<dim3(BB / 64, MM), 512, lds_k4, stream>>>(hid, inter_WT, inter_b, S);
    scores_kernel<<<1, 512, 0, stream>>>(S, ictx2, scores);
    out_kernel<<<BB / 64, 512, lds_k4, stream>>>(hid, scores, out_WT, out_b, out);
}

// Round 3
// 341.145 us; speedup vs baseline: 1.2704x; 1.2704x over previous
//
#include <hip/hip_runtime.h>
#include <hip/hip_bf16.h>

typedef __bf16 bf16;
typedef bf16 bf16x8 __attribute__((ext_vector_type(8)));
typedef float f32x4 __attribute__((ext_vector_type(4)));

#define MFMA16(a, b, c) __builtin_amdgcn_mfma_f32_16x16x32_bf16((a), (b), (c), 0, 0, 0)

// Problem constants
#define MM 3
#define AA 4
#define BB 2048
#define LL 7
#define HH 256
#define VN 50000

__device__ __forceinline__ float ftanh(float x) {
    float e = __expf(2.f * x);
    return 1.f - 2.f / (e + 1.f);
}

// ---------------------------------------------------------------------------
// prep: transposed bf16 weights, cos/sin edge tables, zero S accumulator
// ---------------------------------------------------------------------------
__global__ void prep_kernel(const float* __restrict__ scale_W, const float* __restrict__ attn_W,
                            const float* __restrict__ inter_W, const float* __restrict__ out_W,
                            const float* __restrict__ edge_emb,
                            bf16* __restrict__ scale_WT, bf16* __restrict__ WtopT,
                            bf16* __restrict__ WbotT, bf16* __restrict__ inter_WT,
                            bf16* __restrict__ out_WT,
                            float* __restrict__ ce, float* __restrict__ se,
                            float* __restrict__ S) {
    int idx = blockIdx.x * blockDim.x + threadIdx.x;
    int stride = gridDim.x * blockDim.x;
    for (int i = idx; i < 256 * 256; i += stride) {
        int k = i >> 8, c = i & 255;
        scale_WT[c * 256 + k] = (bf16)scale_W[i];
    }
    for (int i = idx; i < 512 * 256; i += stride) {
        int c = i >> 8, k = i & 255;
        WtopT[c * 256 + k] = (bf16)attn_W[k * 512 + c];
        WbotT[c * 256 + k] = (bf16)attn_W[(256 + k) * 512 + c];
    }
    for (int i = idx; i < 512 * 512; i += stride) {
        int k = i >> 9, c = i & 511;
        inter_WT[c * 512 + k] = (bf16)inter_W[i];
    }
    for (int i = idx; i < 512 * 256; i += stride) {
        int k = i >> 8, c = i & 255;
        out_WT[c * 512 + k] = (bf16)out_W[i];
    }
    for (int i = idx; i < 16 * 128; i += stride) {
        float e = edge_emb[i];
        ce[i] = cosf(e);
        se[i] = sinf(e);
    }
    for (int i = idx; i < 3 * 512; i += stride) S[i] = 0.f;
}

// ---------------------------------------------------------------------------
// K1: scaled_emb[v] = node_emb[v] @ scale_W + scale_b   (bf16 out)  [unchanged]
// ---------------------------------------------------------------------------
__global__ __launch_bounds__(512) void emb_gemm_kernel(
    const float* __restrict__ node_emb, const bf16* __restrict__ scale_WT,
    const float* __restrict__ scale_b, bf16* __restrict__ scaled_emb) {
    extern __shared__ char smem[];
    bf16* Al = (bf16*)smem;                    // [128][264]
    bf16* Wl = (bf16*)(smem + 128 * 264 * 2);  // [128][72]
    const int tid = threadIdx.x;
    const int vb = blockIdx.x * 128;

    for (int i = tid; i < 128 * 64; i += 512) {
        int r = i >> 6, kq = i & 63;
        int v = vb + r;
        float4 x = (v < VN) ? *(const float4*)(node_emb + (size_t)v * 256 + kq * 4)
                            : make_float4(0.f, 0.f, 0.f, 0.f);
        bf16* d = Al + r * 264 + kq * 4;
        d[0] = (bf16)x.x; d[1] = (bf16)x.y; d[2] = (bf16)x.z; d[3] = (bf16)x.w;
    }
    const int w = tid >> 6, l = tid & 63, lr = l & 15, g = l >> 4;
    for (int cc = 0; cc < 2; ++cc) {
        f32x4 acc[8] = {};
        for (int kc = 0; kc < 4; ++kc) {
            __syncthreads();
            for (int i = tid; i < 128 * 8; i += 512) {
                int c = i >> 3, s = i & 7;
                *(bf16x8*)(Wl + c * 72 + s * 8) =
                    *(const bf16x8*)(scale_WT + (cc * 128 + c) * 256 + kc * 64 + s * 8);
            }
            __syncthreads();
#pragma unroll
            for (int kk = 0; kk < 2; ++kk) {
                bf16x8 aF = *(const bf16x8*)(Al + (w * 16 + lr) * 264 + kc * 64 + kk * 32 + g * 8);
#pragma unroll
                for (int ct = 0; ct < 8; ++ct) {
                    bf16x8 bF = *(const bf16x8*)(Wl + (ct * 16 + lr) * 72 + kk * 32 + g * 8);
                    acc[ct] = MFMA16(aF, bF, acc[ct]);
                }
            }
        }
#pragma unroll
        for (int ct = 0; ct < 8; ++ct) {
            int col = cc * 128 + ct * 16 + lr;
            float bia = scale_b[col];
#pragma unroll
            for (int i2 = 0; i2 < 4; ++i2) {
                int v = vb + w * 16 + g * 4 + i2;
                if (v < VN) scaled_emb[(size_t)v * 256 + col] = (bf16)(acc[ct][i2] + bia);
            }
        }
    }
}

// ---------------------------------------------------------------------------
// K3: fused gather + scan + (h0*Wtop pass) + (hp*Wbot W-in-regs GEMM) +
//     logits + softmax + weighted sum + A-reduce -> hid[b][m][512]
// 1024 threads / 16 waves; wave w owns output cols [w*32, w*32+32).
// Al rows q-major: row = q*8 + p.
// ---------------------------------------------------------------------------
#define AR2(q, p) ((((q) * 8) + (p)) * 264)

__global__ __launch_bounds__(1024, 4) void metapath_kernel(
    const int* __restrict__ tokens, const int* __restrict__ etok,
    const bf16* __restrict__ scaled_emb, const bf16* __restrict__ WtopT,
    const bf16* __restrict__ WbotT, const float* __restrict__ attn_b,
    const float* __restrict__ ctx, const float* __restrict__ ce,
    const float* __restrict__ se, float* __restrict__ hid) {
    extern __shared__ char smem[];
    bf16* Al = (bf16*)smem;                                   // 128*264*2 = 67584
    bf16* h0l = (bf16*)(smem + 67584);                        // 16*264*2  =  8448
    float* g0l = (float*)(smem + 67584 + 8448);               // 16*520*4  = 33280
    float* lg = (float*)(smem + 67584 + 8448 + 33280);        // 128*4
    float* wsm = lg + 128;                                    // 128*4  -> total 110336
    const int tid = threadIdx.x;
    const int m = blockIdx.y, bg = blockIdx.x;
    const int w = tid >> 6, l = tid & 63, lr = l & 15, g = l >> 4;

    // Wtop fragments for wave's 32 cols — issue loads early (hide under gather)
    bf16x8 wt[8][2];
#pragma unroll
    for (int ks = 0; ks < 8; ++ks)
#pragma unroll
        for (int ct = 0; ct < 2; ++ct)
            wt[ks][ct] = *(const bf16x8*)(WtopT + (size_t)(w * 32 + ct * 16 + lr) * 256 +
                                          ks * 32 + g * 8);

    if (tid < 128) lg[tid] = 0.f;

    // 1. gather scaled_emb rows (16 q x 8 p), plus h0 copy
    for (int it = 0; it < 4; ++it) {
        int i = tid + it * 1024;
        int row = i >> 5, s = i & 31;
        int q = row >> 3, p = row & 7;
        int a = q >> 2, b = bg * 4 + (q & 3);
        int v = tokens[(((m * AA + a) * BB + b) << 3) + p];
        bf16x8 x = *(const bf16x8*)(scaled_emb + (size_t)v * 256 + s * 8);
        *(bf16x8*)(Al + row * 264 + s * 8) = x;
        if (p == 0) *(bf16x8*)(h0l + q * 264 + s * 8) = x;
    }
    __syncthreads();

    // 2. rotational-encoding scan (in place, rows p>=1)
    for (int it = 0; it < 2; ++it) {
        int i = tid + it * 1024;
        int q = i >> 7, c = i & 127;
        int a = q >> 2, b = bg * 4 + (q & 3);
        const int* eb = etok + ((m * AA + a) * BB + b) * LL;
        float Sr = (float)Al[AR2(q, 0) + c];
        float Si = (float)Al[AR2(q, 0) + c + 128];
        float Pr = 1.f, Pi = 0.f;
#pragma unroll
        for (int k = 1; k <= LL; ++k) {
            int e = eb[k - 1];
            float cr = ce[e * 128 + c], ci = se[e * 128 + c];
            float nPr = Pr * cr - Pi * ci;
            float nPi = Pr * ci + Pi * cr;
            Pr = nPr; Pi = nPi;
            float xr = (float)Al[AR2(q, k) + c];
            float xi = (float)Al[AR2(q, k) + c + 128];
            Sr += Pr * xr - Pi * xi;
            Si += Pr * xi + Pi * xr;
            float inv = 1.f / (float)(k + 1);
            Al[AR2(q, k) + c] = (bf16)(Sr * inv);
            Al[AR2(q, k) + c + 128] = (bf16)(Si * inv);
        }
    }
    __syncthreads();

    // 3. y0 pass: g0l[q][c] = h0[q] . Wtop[:,c] for wave's 32 cols
    {
        f32x4 a0[2] = {};
#pragma unroll
        for (int ks = 0; ks < 8; ++ks) {
            bf16x8 aF = *(const bf16x8*)(h0l + lr * 264 + ks * 32 + g * 8);
#pragma unroll
            for (int ct = 0; ct < 2; ++ct) a0[ct] = MFMA16(aF, wt[ks][ct], a0[ct]);
        }
#pragma unroll
        for (int ct = 0; ct < 2; ++ct) {
            int c = w * 32 + ct * 16 + lr;
#pragma unroll
            for (int i2 = 0; i2 < 4; ++i2) g0l[(g * 4 + i2) * 520 + c] = a0[ct][i2];
        }
    }

    // Wbot fragments (wt is dead now; registers reusable)
    bf16x8 wb[8][2];
#pragma unroll
    for (int ks = 0; ks < 8; ++ks)
#pragma unroll
        for (int ct = 0; ct < 2; ++ct)
            wb[ks][ct] = *(const bf16x8*)(WbotT + (size_t)(w * 32 + ct * 16 + lr) * 256 +
                                          ks * 32 + g * 8);

    float bia[2], cxv[2];
#pragma unroll
    for (int ct = 0; ct < 2; ++ct) {
        int c = w * 32 + ct * 16 + lr;
        bia[ct] = attn_b[c];
        cxv[ct] = ctx[c];
    }

    // 4. Y1 GEMM over 8 row-tiles (16 rows = 2 q x 8 p each) + logit epilogue
    for (int rt = 0; rt < 8; ++rt) {
        f32x4 acc[2] = {};
#pragma unroll
        for (int ks = 0; ks < 8; ++ks) {
            bf16x8 aF = *(const bf16x8*)(Al + (rt * 16 + lr) * 264 + ks * 32 + g * 8);
#pragma unroll
            for (int ct = 0; ct < 2; ++ct) acc[ct] = MFMA16(aF, wb[ks][ct], acc[ct]);
        }
        float pv[4];
#pragma unroll
        for (int i2 = 0; i2 < 4; ++i2) {
            int row = rt * 16 + g * 4 + i2;
            int q = row >> 3;
            float s = 0.f;
#pragma unroll
            for (int ct = 0; ct < 2; ++ct) {
                int c = w * 32 + ct * 16 + lr;
                float z = acc[ct][i2] + g0l[q * 520 + c] + bia[ct];
                s += cxv[ct] * ftanh(z);
            }
            pv[i2] = s;
        }
#pragma unroll
        for (int msk = 1; msk < 16; msk <<= 1)
#pragma unroll
            for (int i2 = 0; i2 < 4; ++i2) pv[i2] += __shfl_xor(pv[i2], msk, 64);
        if (lr == 0) {
#pragma unroll
            for (int i2 = 0; i2 < 4; ++i2) {
                int row = rt * 16 + g * 4 + i2;
                if (row & 7) atomicAdd(&lg[row], pv[i2]);
            }
        }
    }
    __syncthreads();

    // 5. softmax over 7 positions per q
    if (tid < 16) {
        int q = tid;
        float mx = -1e30f;
        for (int j = 1; j <= LL; ++j) mx = fmaxf(mx, lg[q * 8 + j]);
        float ssum = 0.f;
        float ev[LL];
        for (int j = 1; j <= LL; ++j) { ev[j - 1] = __expf(lg[q * 8 + j] - mx); ssum += ev[j - 1]; }
        float inv = 1.f / ssum;
        for (int j = 1; j <= LL; ++j) wsm[q * 8 + j] = ev[j - 1] * inv;
    }
    __syncthreads();

    // 6. weighted sum + relu + sum over a -> hid
    for (int it = 0; it < 2; ++it) {
        int i = tid + it * 1024;
        int bi = i >> 9, c = i & 511;
        float accv = 0.f;
#pragma unroll
        for (int a = 0; a < AA; ++a) {
            int q = a * 4 + bi;
            if (c < 256) {
                accv += fmaxf(0.f, (float)Al[AR2(q, 0) + c]);
            } else {
                float s = 0.f;
#pragma unroll
                for (int j = 1; j <= LL; ++j)
                    s += wsm[q * 8 + j] * (float)Al[AR2(q, j) + (c - 256)];
                accv += fmaxf(0.f, s);
            }
        }
        hid[((size_t)(bg * 4 + bi) * 3 + m) * 512 + c] = accv;
    }
}

// ---------------------------------------------------------------------------
// K4a: S[m][c] += sum_b tanh(hid[b][m] . inter_W[:,c] + inter_b[c])
// W-in-regs, 1024 threads, 64 rows/block, 2 col-passes of 256.
// ---------------------------------------------------------------------------
__global__ __launch_bounds__(1024, 4) void inter_kernel(
    const float* __restrict__ hid, const bf16* __restrict__ inter_WT,
    const float* __restrict__ inter_b, float* __restrict__ S) {
    extern __shared__ char smem[];
    bf16* Al = (bf16*)smem;  // [64][520]
    const int tid = threadIdx.x;
    const int m = blockIdx.y, rb = blockIdx.x * 64;
    const int w = tid >> 6, l = tid & 63, lr = l & 15, g = l >> 4;
    for (int it = 0; it < 8; ++it) {
        int i = tid + it * 1024;
        int r = i >> 7, kq = i & 127;
        float4 x = *(const float4*)(hid + ((size_t)(rb + r) * 3 + m) * 512 + kq * 4);
        bf16* d = Al + r * 520 + kq * 4;
        d[0] = (bf16)x.x; d[1] = (bf16)x.y; d[2] = (bf16)x.z; d[3] = (bf16)x.w;
    }
    __syncthreads();
    for (int cc = 0; cc < 2; ++cc) {
        int c = cc * 256 + w * 16 + lr;
        bf16x8 wf[16];
#pragma unroll
        for (int ks = 0; ks < 16; ++ks)
            wf[ks] = *(const bf16x8*)(inter_WT + (size_t)c * 512 + ks * 32 + g * 8);
        float biav = inter_b[c];
        float csum = 0.f;
        for (int rt = 0; rt < 4; ++rt) {
            f32x4 acc = {};
#pragma unroll
            for (int ks = 0; ks < 16; ++ks) {
                bf16x8 aF = *(const bf16x8*)(Al + (rt * 16 + lr) * 520 + ks * 32 + g * 8);
                acc = MFMA16(aF, wf[ks], acc);
            }
#pragma unroll
            for (int i2 = 0; i2 < 4; ++i2) csum += ftanh(acc[i2] + biav);
        }
        csum += __shfl_xor(csum, 16, 64);
        csum += __shfl_xor(csum, 32, 64);
        if (g == 0) atomicAdd(&S[m * 512 + c], csum);
    }
}

// ---------------------------------------------------------------------------
// K4b: scores[m] = (sum_c S[m][c] * inter_context[c]) / 2048
// ---------------------------------------------------------------------------
__global__ void scores_kernel(const float* __restrict__ S, const float* __restrict__ ictx2,
                              float* __restrict__ scores) {
    __shared__ float red[512];
    int t = threadIdx.x;
    for (int m = 0; m < 3; ++m) {
        red[t] = S[m * 512 + t] * ictx2[t];
        __syncthreads();
        for (int st = 256; st > 0; st >>= 1) {
            if (t < st) red[t] += red[t + st];
            __syncthreads();
        }
        if (t == 0) scores[m] = red[0] * (1.f / 2048.f);
        __syncthreads();
    }
}

// ---------------------------------------------------------------------------
// K4c: out[b] = (sum_m hid[b][m] * scores[m]) @ out_W + out_b   (W-in-regs)
// ---------------------------------------------------------------------------
__global__ __launch_bounds__(1024, 4) void out_kernel(
    const float* __restrict__ hid, const float* __restrict__ scores,
    const bf16* __restrict__ out_WT, const float* __restrict__ out_b,
    float* __restrict__ out) {
    extern __shared__ char smem[];
    bf16* Al = (bf16*)smem;  // [64][520]
    const int tid = threadIdx.x;
    const int rb = blockIdx.x * 64;
    const int w = tid >> 6, l = tid & 63, lr = l & 15, g = l >> 4;
    float s0 = scores[0], s1 = scores[1], s2 = scores[2];
    for (int it = 0; it < 8; ++it) {
        int i = tid + it * 1024;
        int r = i >> 7, kq = i & 127;
        const float* hp = hid + (size_t)(rb + r) * 1536 + kq * 4;
        float4 x0 = *(const float4*)(hp);
        float4 x1 = *(const float4*)(hp + 512);
        float4 x2 = *(const float4*)(hp + 1024);
        bf16* d = Al + r * 520 + kq * 4;
        d[0] = (bf16)(x0.x * s0 + x1.x * s1 + x2.x * s2);
        d[1] = (bf16)(x0.y * s0 + x1.y * s1 + x2.y * s2);
        d[2] = (bf16)(x0.z * s0 + x1.z * s1 + x2.z * s2);
        d[3] = (bf16)(x0.w * s0 + x1.w * s1 + x2.w * s2);
    }
    __syncthreads();
    int c = w * 16 + lr;
    bf16x8 wf[16];
#pragma unroll
    for (int ks = 0; ks < 16; ++ks)
        wf[ks] = *(const bf16x8*)(out_WT + (size_t)c * 512 + ks * 32 + g * 8);
    float biav = out_b[c];
    for (int rt = 0; rt < 4; ++rt) {
        f32x4 acc = {};
#pragma unroll
        for (int ks = 0; ks < 16; ++ks) {
            bf16x8 aF = *(const bf16x8*)(Al + (rt * 16 + lr) * 520 + ks * 32 + g * 8);
            acc = MFMA16(aF, wf[ks], acc);
        }
#pragma unroll
        for (int i2 = 0; i2 < 4; ++i2)
            out[(size_t)(rb + rt * 16 + g * 4 + i2) * 256 + c] = acc[i2] + biav;
    }
}

// ---------------------------------------------------------------------------
extern "C" void kernel_launch(void* const* d_in, const int* in_sizes, int n_in,
                              void* d_out, int out_size, void* d_ws, size_t ws_size,
                              hipStream_t stream) {
    const int* tokens = (const int*)d_in[0];
    const int* etok = (const int*)d_in[1];
    const float* node_emb = (const float*)d_in[2];
    const float* edge_emb = (const float*)d_in[3];
    const float* scale_W = (const float*)d_in[4];
    const float* scale_b = (const float*)d_in[5];
    const float* attn_W = (const float*)d_in[6];
    const float* attn_b = (const float*)d_in[7];
    const float* ictx = (const float*)d_in[8];
    const float* inter_W = (const float*)d_in[9];
    const float* inter_b = (const float*)d_in[10];
    const float* ictx2 = (const float*)d_in[11];
    const float* out_W = (const float*)d_in[12];
    const float* out_b = (const float*)d_in[13];
    float* out = (float*)d_out;
    char* ws = (char*)d_ws;

    // ws layout (bytes) — total identical to round-0 proven budget (39.65 MB)
    size_t off = 0;
    bf16* scale_WT = (bf16*)(ws + off); off += 256 * 256 * 2;            // 131072
    bf16* WtopT = (bf16*)(ws + off);    off += 512 * 256 * 2;            // 262144
    bf16* WbotT = (bf16*)(ws + off);    off += 512 * 256 * 2;            // 262144
    bf16* inter_WT = (bf16*)(ws + off); off += 512 * 512 * 2;            // 524288
    bf16* out_WT = (bf16*)(ws + off);   off += 512 * 256 * 2;            // 262144
    float* ce = (float*)(ws + off);     off += 16 * 128 * 4;             // 8192
    float* se = (float*)(ws + off);     off += 16 * 128 * 4;             // 8192
    float* S = (float*)(ws + off);      off += 3 * 512 * 4;              // 6144
    float* scores = (float*)(ws + off); off += 256;
    bf16* scaled_emb = (bf16*)(ws + off); off += (size_t)VN * 256 * 2;   // 25.6 MB
    float* hid = (float*)(ws + off);    off += (size_t)BB * 3 * 512 * 4; // 12.6 MB
    if (ws_size < off) return;  // insufficient scratch -> fail loudly (zeros)

    const int lds_k1 = 128 * 264 * 2 + 128 * 72 * 2;   // 86016
    const int lds_k3 = 67584 + 8448 + 33280 + 1024;    // 110336
    const int lds_k4 = 64 * 520 * 2;                   // 66560
    (void)hipFuncSetAttribute((const void*)emb_gemm_kernel,
                              hipFuncAttributeMaxDynamicSharedMemorySize, lds_k1);
    (void)hipFuncSetAttribute((const void*)metapath_kernel,
                              hipFuncAttributeMaxDynamicSharedMemorySize, lds_k3);
    (void)hipFuncSetAttribute((const void*)inter_kernel,
                              hipFuncAttributeMaxDynamicSharedMemorySize, lds_k4);
    (void)hipFuncSetAttribute((const void*)out_kernel,
                              hipFuncAttributeMaxDynamicSharedMemorySize, lds_k4);

    prep_kernel<<<1024, 256, 0, stream>>>(scale_W, attn_W, inter_W, out_W, edge_emb,
                                          scale_WT, WtopT, WbotT, inter_WT, out_WT, ce, se, S);
    emb_gemm_kernel<<<(VN + 127) / 128, 512, lds_k1, stream>>>(node_emb, scale_WT, scale_b,
                                                               scaled_emb);
    metapath_kernel<<<dim3(BB / 4, MM), 1024, lds_k3, stream>>>(tokens, etok, scaled_emb,
                                                                WtopT, WbotT, attn_b, ictx,
                                                                ce, se, hid);
    inter_kernel<<<dim3(BB / 64, MM), 1024, lds_k4, stream>>>(hid, inter_WT, inter_b, S);
    scores_kernel<<<1, 512, 0, stream>>>(S, ictx2, scores);
    out_kernel<<<BB / 64, 1024, lds_k4, stream>>>(hid, scores, out_WT, out_b, out);
}

// Round 4
// 303.735 us; speedup vs baseline: 1.4268x; 1.1232x over previous
//
#include <hip/hip_runtime.h>
#include <hip/hip_bf16.h>

typedef __bf16 bf16;
typedef bf16 bf16x8 __attribute__((ext_vector_type(8)));
typedef float f32x4 __attribute__((ext_vector_type(4)));

#define MFMA16(a, b, c) __builtin_amdgcn_mfma_f32_16x16x32_bf16((a), (b), (c), 0, 0, 0)

// Problem constants
#define MM 3
#define AA 4
#define BB 2048
#define LL 7
#define HH 256
#define VN 50000

__device__ __forceinline__ float ftanh(float x) {
    float e = __expf(2.f * x);
    float r = __builtin_amdgcn_rcpf(e + 1.f);
    return 1.f - 2.f * r;
}
__device__ __forceinline__ float bf2f(unsigned u) {
    union { unsigned u; float f; } x; x.u = u << 16; return x.f;
}
__device__ __forceinline__ unsigned f2bf(float f) {
    bf16 b = (bf16)f;
    return (unsigned)__builtin_bit_cast(unsigned short, b);
}

// ---------------------------------------------------------------------------
// prep: transposed bf16 weights, cos/sin edge tables, zero S accumulator
// ---------------------------------------------------------------------------
__global__ void prep_kernel(const float* __restrict__ scale_W, const float* __restrict__ attn_W,
                            const float* __restrict__ inter_W, const float* __restrict__ out_W,
                            const float* __restrict__ edge_emb,
                            bf16* __restrict__ scale_WT, bf16* __restrict__ WtopT,
                            bf16* __restrict__ WbotT, bf16* __restrict__ inter_WT,
                            bf16* __restrict__ out_WT,
                            float* __restrict__ ce, float* __restrict__ se,
                            float* __restrict__ S) {
    int idx = blockIdx.x * blockDim.x + threadIdx.x;
    int stride = gridDim.x * blockDim.x;
    for (int i = idx; i < 256 * 256; i += stride) {
        int k = i >> 8, c = i & 255;
        scale_WT[c * 256 + k] = (bf16)scale_W[i];
    }
    for (int i = idx; i < 512 * 256; i += stride) {
        int c = i >> 8, k = i & 255;
        WtopT[c * 256 + k] = (bf16)attn_W[k * 512 + c];
        WbotT[c * 256 + k] = (bf16)attn_W[(256 + k) * 512 + c];
    }
    for (int i = idx; i < 512 * 512; i += stride) {
        int k = i >> 9, c = i & 511;
        inter_WT[c * 512 + k] = (bf16)inter_W[i];
    }
    for (int i = idx; i < 512 * 256; i += stride) {
        int k = i >> 8, c = i & 255;
        out_WT[c * 512 + k] = (bf16)out_W[i];
    }
    for (int i = idx; i < 16 * 128; i += stride) {
        float e = edge_emb[i];
        ce[i] = cosf(e);
        se[i] = sinf(e);
    }
    for (int i = idx; i < 3 * 512; i += stride) S[i] = 0.f;
}

// ---------------------------------------------------------------------------
// K1: scaled_emb[v] = node_emb[v] @ scale_W + scale_b  — 64-row W-in-regs,
// single barrier, 512 thr / 8 waves x 32 cols.
// ---------------------------------------------------------------------------
__global__ __launch_bounds__(512, 4) void emb_gemm_kernel(
    const float* __restrict__ node_emb, const bf16* __restrict__ scale_WT,
    const float* __restrict__ scale_b, bf16* __restrict__ scaled_emb) {
    extern __shared__ char smem[];
    bf16* Al = (bf16*)smem;  // [64][264] = 33792 B
    const int tid = threadIdx.x;
    const int vb = blockIdx.x * 64;
    const int w = tid >> 6, l = tid & 63, lr = l & 15, g = l >> 4;

    // W fragments first (hide latency under staging)
    bf16x8 wf[8][2];
#pragma unroll
    for (int ks = 0; ks < 8; ++ks)
#pragma unroll
        for (int ct = 0; ct < 2; ++ct)
            wf[ks][ct] = *(const bf16x8*)(scale_WT + (size_t)(w * 32 + ct * 16 + lr) * 256 +
                                          ks * 32 + g * 8);
    float bia[2];
#pragma unroll
    for (int ct = 0; ct < 2; ++ct) bia[ct] = scale_b[w * 32 + ct * 16 + lr];

    for (int it = 0; it < 8; ++it) {
        int i = tid + it * 512;
        int r = i >> 6, kq = i & 63;
        int v = vb + r;
        float4 x = (v < VN) ? *(const float4*)(node_emb + (size_t)v * 256 + kq * 4)
                            : make_float4(0.f, 0.f, 0.f, 0.f);
        bf16* d = Al + r * 264 + kq * 4;
        d[0] = (bf16)x.x; d[1] = (bf16)x.y; d[2] = (bf16)x.z; d[3] = (bf16)x.w;
    }
    __syncthreads();

    for (int rt = 0; rt < 4; ++rt) {
        f32x4 acc[2] = {};
#pragma unroll
        for (int ks = 0; ks < 8; ++ks) {
            bf16x8 aF = *(const bf16x8*)(Al + (rt * 16 + lr) * 264 + ks * 32 + g * 8);
#pragma unroll
            for (int ct = 0; ct < 2; ++ct) acc[ct] = MFMA16(aF, wf[ks][ct], acc[ct]);
        }
#pragma unroll
        for (int ct = 0; ct < 2; ++ct) {
            int col = w * 32 + ct * 16 + lr;
#pragma unroll
            for (int i2 = 0; i2 < 4; ++i2) {
                int v = vb + rt * 16 + g * 4 + i2;
                if (v < VN) scaled_emb[(size_t)v * 256 + col] = (bf16)(acc[ct][i2] + bia[ct]);
            }
        }
    }
}

// ---------------------------------------------------------------------------
// K3: fused gather + scan + split attn GEMM + logits + softmax + weighted sum
// 512 thr / 8 waves; block owns 8 q (4a x 2b); wave owns 32 cols x 2 passes.
// Al rows q-major: row = q*8 + p (64 rows).
// ---------------------------------------------------------------------------
#define AR2(q, p) ((((q) * 8) + (p)) * 264)

__global__ __launch_bounds__(512, 4) void metapath_kernel(
    const int* __restrict__ tokens, const int* __restrict__ etok,
    const bf16* __restrict__ scaled_emb, const bf16* __restrict__ WtopT,
    const bf16* __restrict__ WbotT, const float* __restrict__ attn_b,
    const float* __restrict__ ctx, const float* __restrict__ ce,
    const float* __restrict__ se, float* __restrict__ hid) {
    extern __shared__ char smem[];
    bf16* Al = (bf16*)smem;                       // 64*264*2 = 33792
    bf16* h0l = (bf16*)(smem + 33792);            // 8*264*2  =  4224
    float* g0l = (float*)(smem + 38016);          // 8*520*4  = 16640
    float* lg = (float*)(smem + 54656);           // 64*4
    float* wsm = (float*)(smem + 54912);          // 64*4  -> total 55168
    const int tid = threadIdx.x;
    const int m = blockIdx.y, bg = blockIdx.x;    // bg: group of 2 b's
    const int w = tid >> 6, l = tid & 63, lr = l & 15, g = l >> 4;

    // pass-0 Wtop fragments early (hide under gather)
    bf16x8 wt[8][2];
#pragma unroll
    for (int ks = 0; ks < 8; ++ks)
#pragma unroll
        for (int ct = 0; ct < 2; ++ct)
            wt[ks][ct] = *(const bf16x8*)(WtopT + (size_t)(w * 32 + ct * 16 + lr) * 256 +
                                          ks * 32 + g * 8);

    if (tid < 64) lg[tid] = 0.f;

    // 1. gather: 64 rows (8q x 8p) x 32 chunks of 16B
    for (int it = 0; it < 4; ++it) {
        int i = tid + it * 512;
        int row = i >> 5, s = i & 31;
        int q = row >> 3, p = row & 7;
        int a = q >> 1, b = bg * 2 + (q & 1);
        int v = tokens[(((m * AA + a) * BB + b) << 3) + p];
        bf16x8 x = *(const bf16x8*)(scaled_emb + (size_t)v * 256 + s * 8);
        *(bf16x8*)(Al + row * 264 + s * 8) = x;
        if (p == 0) *(bf16x8*)(h0l + q * 264 + s * 8) = x;
    }
    __syncthreads();

    // 2. rotational scan, c-pairs packed in b32 (1 pair per thread)
    {
        int q = tid >> 6, cp = tid & 63;
        int c0 = cp * 2;
        int a = q >> 1, b = bg * 2 + (q & 1);
        const int* eb = etok + ((m * AA + a) * BB + b) * LL;
        unsigned ur = *(const unsigned*)(Al + AR2(q, 0) + c0);
        unsigned ui = *(const unsigned*)(Al + AR2(q, 0) + c0 + 128);
        float Sr0 = bf2f(ur & 0xffffu), Sr1 = bf2f(ur >> 16);
        float Si0 = bf2f(ui & 0xffffu), Si1 = bf2f(ui >> 16);
        float P0r = 1.f, P0i = 0.f, P1r = 1.f, P1i = 0.f;
#pragma unroll
        for (int k = 1; k <= LL; ++k) {
            int e = eb[k - 1];
            float2 crv = *(const float2*)(ce + e * 128 + c0);
            float2 civ = *(const float2*)(se + e * 128 + c0);
            float t0r = P0r * crv.x - P0i * civ.x, t0i = P0r * civ.x + P0i * crv.x;
            float t1r = P1r * crv.y - P1i * civ.y, t1i = P1r * civ.y + P1i * crv.y;
            P0r = t0r; P0i = t0i; P1r = t1r; P1i = t1i;
            unsigned xr = *(const unsigned*)(Al + AR2(q, k) + c0);
            unsigned xi = *(const unsigned*)(Al + AR2(q, k) + c0 + 128);
            float xr0 = bf2f(xr & 0xffffu), xr1 = bf2f(xr >> 16);
            float xi0 = bf2f(xi & 0xffffu), xi1 = bf2f(xi >> 16);
            Sr0 += P0r * xr0 - P0i * xi0; Si0 += P0r * xi0 + P0i * xr0;
            Sr1 += P1r * xr1 - P1i * xi1; Si1 += P1r * xi1 + P1i * xr1;
            float inv = 1.f / (float)(k + 1);
            *(unsigned*)(Al + AR2(q, k) + c0) = f2bf(Sr0 * inv) | (f2bf(Sr1 * inv) << 16);
            *(unsigned*)(Al + AR2(q, k) + c0 + 128) = f2bf(Si0 * inv) | (f2bf(Si1 * inv) << 16);
        }
    }
    __syncthreads();

    // 3+4. two col-passes: y0 (Wtop) -> g0l; then Y1 (Wbot) + logit epilogue
    bf16x8 wb[8][2];
    for (int cc = 0; cc < 2; ++cc) {
        if (cc) {
#pragma unroll
            for (int ks = 0; ks < 8; ++ks)
#pragma unroll
                for (int ct = 0; ct < 2; ++ct)
                    wt[ks][ct] = *(const bf16x8*)(WtopT +
                                                  (size_t)(256 + w * 32 + ct * 16 + lr) * 256 +
                                                  ks * 32 + g * 8);
        }
        // y0: rows 0..7 real (8..15 dummy, unwritten)
        f32x4 a0[2] = {};
#pragma unroll
        for (int ks = 0; ks < 8; ++ks) {
            bf16x8 aF = *(const bf16x8*)(h0l + lr * 264 + ks * 32 + g * 8);
#pragma unroll
            for (int ct = 0; ct < 2; ++ct) a0[ct] = MFMA16(aF, wt[ks][ct], a0[ct]);
        }
#pragma unroll
        for (int ct = 0; ct < 2; ++ct) {
            int c = cc * 256 + w * 32 + ct * 16 + lr;
#pragma unroll
            for (int i2 = 0; i2 < 4; ++i2) {
                int row = g * 4 + i2;
                if (row < 8) g0l[row * 520 + c] = a0[ct][i2];
            }
        }
        // Wbot fragments for this pass (wt dead)
#pragma unroll
        for (int ks = 0; ks < 8; ++ks)
#pragma unroll
            for (int ct = 0; ct < 2; ++ct)
                wb[ks][ct] = *(const bf16x8*)(WbotT +
                                              (size_t)(cc * 256 + w * 32 + ct * 16 + lr) * 256 +
                                              ks * 32 + g * 8);
        float bia[2], cxv[2];
#pragma unroll
        for (int ct = 0; ct < 2; ++ct) {
            int c = cc * 256 + w * 32 + ct * 16 + lr;
            bia[ct] = attn_b[c];
            cxv[ct] = ctx[c];
        }
        // Y1 over 4 row-tiles (16 rows = 2q x 8p each)
        for (int rt = 0; rt < 4; ++rt) {
            f32x4 acc[2] = {};
#pragma unroll
            for (int ks = 0; ks < 8; ++ks) {
                bf16x8 aF = *(const bf16x8*)(Al + (rt * 16 + lr) * 264 + ks * 32 + g * 8);
#pragma unroll
                for (int ct = 0; ct < 2; ++ct) acc[ct] = MFMA16(aF, wb[ks][ct], acc[ct]);
            }
            float pv[4];
#pragma unroll
            for (int i2 = 0; i2 < 4; ++i2) {
                int row = rt * 16 + g * 4 + i2;
                int q = row >> 3;
                float s = 0.f;
#pragma unroll
                for (int ct = 0; ct < 2; ++ct) {
                    int c = cc * 256 + w * 32 + ct * 16 + lr;
                    float z = acc[ct][i2] + g0l[q * 520 + c] + bia[ct];
                    s += cxv[ct] * ftanh(z);
                }
                pv[i2] = s;
            }
#pragma unroll
            for (int msk = 1; msk < 16; msk <<= 1)
#pragma unroll
                for (int i2 = 0; i2 < 4; ++i2) pv[i2] += __shfl_xor(pv[i2], msk, 64);
            if (lr == 0) {
#pragma unroll
                for (int i2 = 0; i2 < 4; ++i2) {
                    int row = rt * 16 + g * 4 + i2;
                    if (row & 7) atomicAdd(&lg[row], pv[i2]);
                }
            }
        }
    }
    __syncthreads();

    // 5. softmax over 7 positions per q
    if (tid < 8) {
        int q = tid;
        float mx = -1e30f;
        for (int j = 1; j <= LL; ++j) mx = fmaxf(mx, lg[q * 8 + j]);
        float ssum = 0.f, ev[LL];
        for (int j = 1; j <= LL; ++j) { ev[j - 1] = __expf(lg[q * 8 + j] - mx); ssum += ev[j - 1]; }
        float inv = 1.f / ssum;
        for (int j = 1; j <= LL; ++j) wsm[q * 8 + j] = ev[j - 1] * inv;
    }
    __syncthreads();

    // 6. weighted sum + relu + A-reduce -> hid  (c-pairs, 1 per thread)
    {
        int bi = tid >> 8, cp = tid & 255;
        int c0 = cp * 2;
        float acc0 = 0.f, acc1 = 0.f;
        if (c0 < 256) {
#pragma unroll
            for (int a = 0; a < AA; ++a) {
                int q = a * 2 + bi;
                unsigned u = *(const unsigned*)(Al + AR2(q, 0) + c0);
                acc0 += fmaxf(0.f, bf2f(u & 0xffffu));
                acc1 += fmaxf(0.f, bf2f(u >> 16));
            }
        } else {
            int cb = c0 - 256;
#pragma unroll
            for (int a = 0; a < AA; ++a) {
                int q = a * 2 + bi;
                float s0 = 0.f, s1 = 0.f;
#pragma unroll
                for (int j = 1; j <= LL; ++j) {
                    unsigned u = *(const unsigned*)(Al + AR2(q, j) + cb);
                    float wj = wsm[q * 8 + j];
                    s0 += wj * bf2f(u & 0xffffu);
                    s1 += wj * bf2f(u >> 16);
                }
                acc0 += fmaxf(0.f, s0);
                acc1 += fmaxf(0.f, s1);
            }
        }
        float2 o; o.x = acc0; o.y = acc1;
        *(float2*)(hid + ((size_t)(bg * 2 + bi) * 3 + m) * 512 + c0) = o;
    }
}

// ---------------------------------------------------------------------------
// K4a: S[m][c] += sum_b tanh(hid[b][m] . inter_W[:,c] + inter_b[c])
// 32 rows/block, W-in-regs, 1024 thr / 16 waves x 16 cols x 2 passes.
// ---------------------------------------------------------------------------
__global__ __launch_bounds__(1024, 4) void inter_kernel(
    const float* __restrict__ hid, const bf16* __restrict__ inter_WT,
    const float* __restrict__ inter_b, float* __restrict__ S) {
    extern __shared__ char smem[];
    bf16* Al = (bf16*)smem;  // [32][520] = 33280 B
    const int tid = threadIdx.x;
    const int m = blockIdx.y, rb = blockIdx.x * 32;
    const int w = tid >> 6, l = tid & 63, lr = l & 15, g = l >> 4;
    for (int it = 0; it < 4; ++it) {
        int i = tid + it * 1024;
        int r = i >> 7, kq = i & 127;
        float4 x = *(const float4*)(hid + ((size_t)(rb + r) * 3 + m) * 512 + kq * 4);
        bf16* d = Al + r * 520 + kq * 4;
        d[0] = (bf16)x.x; d[1] = (bf16)x.y; d[2] = (bf16)x.z; d[3] = (bf16)x.w;
    }
    __syncthreads();
    for (int cc = 0; cc < 2; ++cc) {
        int c = cc * 256 + w * 16 + lr;
        bf16x8 wf[16];
#pragma unroll
        for (int ks = 0; ks < 16; ++ks)
            wf[ks] = *(const bf16x8*)(inter_WT + (size_t)c * 512 + ks * 32 + g * 8);
        float biav = inter_b[c];
        float csum = 0.f;
        for (int rt = 0; rt < 2; ++rt) {
            f32x4 acc = {};
#pragma unroll
            for (int ks = 0; ks < 16; ++ks) {
                bf16x8 aF = *(const bf16x8*)(Al + (rt * 16 + lr) * 520 + ks * 32 + g * 8);
                acc = MFMA16(aF, wf[ks], acc);
            }
#pragma unroll
            for (int i2 = 0; i2 < 4; ++i2) csum += ftanh(acc[i2] + biav);
        }
        csum += __shfl_xor(csum, 16, 64);
        csum += __shfl_xor(csum, 32, 64);
        if (g == 0) atomicAdd(&S[m * 512 + c], csum);
    }
}

// ---------------------------------------------------------------------------
// K4b: scores[m] = (sum_c S[m][c] * inter_context[c]) / 2048
// ---------------------------------------------------------------------------
__global__ void scores_kernel(const float* __restrict__ S, const float* __restrict__ ictx2,
                              float* __restrict__ scores) {
    __shared__ float red[512];
    int t = threadIdx.x;
    for (int m = 0; m < 3; ++m) {
        red[t] = S[m * 512 + t] * ictx2[t];
        __syncthreads();
        for (int st = 256; st > 0; st >>= 1) {
            if (t < st) red[t] += red[t + st];
            __syncthreads();
        }
        if (t == 0) scores[m] = red[0] * (1.f / 2048.f);
        __syncthreads();
    }
}

// ---------------------------------------------------------------------------
// K4c: out[b] = (sum_m hid[b][m] * scores[m]) @ out_W + out_b
// 32 rows/block, W-in-regs, 1024 thr / 16 waves x 16 cols.
// ---------------------------------------------------------------------------
__global__ __launch_bounds__(1024, 4) void out_kernel(
    const float* __restrict__ hid, const float* __restrict__ scores,
    const bf16* __restrict__ out_WT, const float* __restrict__ out_b,
    float* __restrict__ out) {
    extern __shared__ char smem[];
    bf16* Al = (bf16*)smem;  // [32][520] = 33280 B
    const int tid = threadIdx.x;
    const int rb = blockIdx.x * 32;
    const int w = tid >> 6, l = tid & 63, lr = l & 15, g = l >> 4;
    float s0 = scores[0], s1 = scores[1], s2 = scores[2];
    for (int it = 0; it < 4; ++it) {
        int i = tid + it * 1024;
        int r = i >> 7, kq = i & 127;
        const float* hp = hid + (size_t)(rb + r) * 1536 + kq * 4;
        float4 x0 = *(const float4*)(hp);
        float4 x1 = *(const float4*)(hp + 512);
        float4 x2 = *(const float4*)(hp + 1024);
        bf16* d = Al + r * 520 + kq * 4;
        d[0] = (bf16)(x0.x * s0 + x1.x * s1 + x2.x * s2);
        d[1] = (bf16)(x0.y * s0 + x1.y * s1 + x2.y * s2);
        d[2] = (bf16)(x0.z * s0 + x1.z * s1 + x2.z * s2);
        d[3] = (bf16)(x0.w * s0 + x1.w * s1 + x2.w * s2);
    }
    __syncthreads();
    int c = w * 16 + lr;
    bf16x8 wf[16];
#pragma unroll
    for (int ks = 0; ks < 16; ++ks)
        wf[ks] = *(const bf16x8*)(out_WT + (size_t)c * 512 + ks * 32 + g * 8);
    float biav = out_b[c];
    for (int rt = 0; rt < 2; ++rt) {
        f32x4 acc = {};
#pragma unroll
        for (int ks = 0; ks < 16; ++ks) {
            bf16x8 aF = *(const bf16x8*)(Al + (rt * 16 + lr) * 520 + ks * 32 + g * 8);
            acc = MFMA16(aF, wf[ks], acc);
        }
#pragma unroll
        for (int i2 = 0; i2 < 4; ++i2)
            out[(size_t)(rb + rt * 16 + g * 4 + i2) * 256 + c] = acc[i2] + biav;
    }
}

// ---------------------------------------------------------------------------
extern "C" void kernel_launch(void* const* d_in, const int* in_sizes, int n_in,
                              void* d_out, int out_size, void* d_ws, size_t ws_size,
                              hipStream_t stream) {
    const int* tokens = (const int*)d_in[0];
    const int* etok = (const int*)d_in[1];
    const float* node_emb = (const float*)d_in[2];
    const float* edge_emb = (const float*)d_in[3];
    const float* scale_W = (const float*)d_in[4];
    const float* scale_b = (const float*)d_in[5];
    const float* attn_W = (const float*)d_in[6];
    const float* attn_b = (const float*)d_in[7];
    const float* ictx = (const float*)d_in[8];
    const float* inter_W = (const float*)d_in[9];
    const float* inter_b = (const float*)d_in[10];
    const float* ictx2 = (const float*)d_in[11];
    const float* out_W = (const float*)d_in[12];
    const float* out_b = (const float*)d_in[13];
    float* out = (float*)d_out;
    char* ws = (char*)d_ws;

    // ws layout (bytes) — total identical to proven 39.65 MB budget
    size_t off = 0;
    bf16* scale_WT = (bf16*)(ws + off); off += 256 * 256 * 2;            // 131072
    bf16* WtopT = (bf16*)(ws + off);    off += 512 * 256 * 2;            // 262144
    bf16* WbotT = (bf16*)(ws + off);    off += 512 * 256 * 2;            // 262144
    bf16* inter_WT = (bf16*)(ws + off); off += 512 * 512 * 2;            // 524288
    bf16* out_WT = (bf16*)(ws + off);   off += 512 * 256 * 2;            // 262144
    float* ce = (float*)(ws + off);     off += 16 * 128 * 4;             // 8192
    float* se = (float*)(ws + off);     off += 16 * 128 * 4;             // 8192
    float* S = (float*)(ws + off);      off += 3 * 512 * 4;              // 6144
    float* scores = (float*)(ws + off); off += 256;
    bf16* scaled_emb = (bf16*)(ws + off); off += (size_t)VN * 256 * 2;   // 25.6 MB
    float* hid = (float*)(ws + off);    off += (size_t)BB * 3 * 512 * 4; // 12.6 MB
    if (ws_size < off) return;  // insufficient scratch -> fail loudly (zeros)

    const int lds_k1 = 64 * 264 * 2;   // 33792
    const int lds_k3 = 55168;          // Al+h0l+g0l+lg+wsm
    const int lds_k4 = 32 * 520 * 2;   // 33280

    prep_kernel<<<1024, 256, 0, stream>>>(scale_W, attn_W, inter_W, out_W, edge_emb,
                                          scale_WT, WtopT, WbotT, inter_WT, out_WT, ce, se, S);
    emb_gemm_kernel<<<(VN + 63) / 64, 512, lds_k1, stream>>>(node_emb, scale_WT, scale_b,
                                                             scaled_emb);
    metapath_kernel<<<dim3(BB / 2, MM), 512, lds_k3, stream>>>(tokens, etok, scaled_emb,
                                                               WtopT, WbotT, attn_b, ictx,
                                                               ce, se, hid);
    inter_kernel<<<dim3(BB / 32, MM), 1024, lds_k4, stream>>>(hid, inter_WT, inter_b, S);
    scores_kernel<<<1, 512, 0, stream>>>(S, ictx2, scores);
    out_kernel<<<BB / 32, 1024, lds_k4, stream>>>(hid, scores, out_WT, out_b, out);
}

// Round 5
// 292.012 us; speedup vs baseline: 1.4841x; 1.0401x over previous
//
#include <hip/hip_runtime.h>
#include <hip/hip_bf16.h>

typedef __bf16 bf16;
typedef bf16 bf16x8 __attribute__((ext_vector_type(8)));
typedef float f32x4 __attribute__((ext_vector_type(4)));

#define MFMA16(a, b, c) __builtin_amdgcn_mfma_f32_16x16x32_bf16((a), (b), (c), 0, 0, 0)

// Problem constants
#define MM 3
#define AA 4
#define BB 2048
#define LL 7
#define HH 256
#define VN 50000

__device__ __forceinline__ float ftanh(float x) {
    float e = __expf(2.f * x);
    float r = __builtin_amdgcn_rcpf(e + 1.f);
    return 1.f - 2.f * r;
}
__device__ __forceinline__ float bf2f(unsigned u) {
    union { unsigned u; float f; } x; x.u = u << 16; return x.f;
}
__device__ __forceinline__ unsigned f2bf(float f) {
    bf16 b = (bf16)f;
    return (unsigned)__builtin_bit_cast(unsigned short, b);
}

// ---------------------------------------------------------------------------
// prep: transposed bf16 weights, cos/sin edge tables, zero S accumulator
// ---------------------------------------------------------------------------
__global__ void prep_kernel(const float* __restrict__ scale_W, const float* __restrict__ attn_W,
                            const float* __restrict__ inter_W, const float* __restrict__ out_W,
                            const float* __restrict__ edge_emb,
                            bf16* __restrict__ scale_WT, bf16* __restrict__ WtopT,
                            bf16* __restrict__ WbotT, bf16* __restrict__ inter_WT,
                            bf16* __restrict__ out_WT,
                            float* __restrict__ ce, float* __restrict__ se,
                            float* __restrict__ S) {
    int idx = blockIdx.x * blockDim.x + threadIdx.x;
    int stride = gridDim.x * blockDim.x;
    for (int i = idx; i < 256 * 256; i += stride) {
        int k = i >> 8, c = i & 255;
        scale_WT[c * 256 + k] = (bf16)scale_W[i];
    }
    for (int i = idx; i < 512 * 256; i += stride) {
        int c = i >> 8, k = i & 255;
        WtopT[c * 256 + k] = (bf16)attn_W[k * 512 + c];
        WbotT[c * 256 + k] = (bf16)attn_W[(256 + k) * 512 + c];
    }
    for (int i = idx; i < 512 * 512; i += stride) {
        int k = i >> 9, c = i & 511;
        inter_WT[c * 512 + k] = (bf16)inter_W[i];
    }
    for (int i = idx; i < 512 * 256; i += stride) {
        int k = i >> 8, c = i & 255;
        out_WT[c * 512 + k] = (bf16)out_W[i];
    }
    for (int i = idx; i < 16 * 128; i += stride) {
        float e = edge_emb[i];
        ce[i] = cosf(e);
        se[i] = sinf(e);
    }
    for (int i = idx; i < 3 * 512; i += stride) S[i] = 0.f;
}

// ---------------------------------------------------------------------------
// K1: scaled_emb[v] = node_emb[v] @ scale_W + scale_b  — 64-row W-in-regs
// ---------------------------------------------------------------------------
__global__ __launch_bounds__(512, 4) void emb_gemm_kernel(
    const float* __restrict__ node_emb, const bf16* __restrict__ scale_WT,
    const float* __restrict__ scale_b, bf16* __restrict__ scaled_emb) {
    extern __shared__ char smem[];
    bf16* Al = (bf16*)smem;  // [64][264] = 33792 B
    const int tid = threadIdx.x;
    const int vb = blockIdx.x * 64;
    const int w = tid >> 6, l = tid & 63, lr = l & 15, g = l >> 4;

    bf16x8 wf[8][2];
#pragma unroll
    for (int ks = 0; ks < 8; ++ks)
#pragma unroll
        for (int ct = 0; ct < 2; ++ct)
            wf[ks][ct] = *(const bf16x8*)(scale_WT + (size_t)(w * 32 + ct * 16 + lr) * 256 +
                                          ks * 32 + g * 8);
    float bia[2];
#pragma unroll
    for (int ct = 0; ct < 2; ++ct) bia[ct] = scale_b[w * 32 + ct * 16 + lr];

    for (int it = 0; it < 8; ++it) {
        int i = tid + it * 512;
        int r = i >> 6, kq = i & 63;
        int v = vb + r;
        float4 x = (v < VN) ? *(const float4*)(node_emb + (size_t)v * 256 + kq * 4)
                            : make_float4(0.f, 0.f, 0.f, 0.f);
        bf16* d = Al + r * 264 + kq * 4;
        d[0] = (bf16)x.x; d[1] = (bf16)x.y; d[2] = (bf16)x.z; d[3] = (bf16)x.w;
    }
    __syncthreads();

    for (int rt = 0; rt < 4; ++rt) {
        f32x4 acc[2] = {};
#pragma unroll
        for (int ks = 0; ks < 8; ++ks) {
            bf16x8 aF = *(const bf16x8*)(Al + (rt * 16 + lr) * 264 + ks * 32 + g * 8);
#pragma unroll
            for (int ct = 0; ct < 2; ++ct) acc[ct] = MFMA16(aF, wf[ks][ct], acc[ct]);
        }
#pragma unroll
        for (int ct = 0; ct < 2; ++ct) {
            int col = w * 32 + ct * 16 + lr;
#pragma unroll
            for (int i2 = 0; i2 < 4; ++i2) {
                int v = vb + rt * 16 + g * 4 + i2;
                if (v < VN) scaled_emb[(size_t)v * 256 + col] = (bf16)(acc[ct][i2] + bia[ct]);
            }
        }
    }
}

// ---------------------------------------------------------------------------
// K3: fused gather + scan + split attn GEMM + logits + softmax + weighted sum
// 512 thr / 8 waves; 8 q (4a x 2b); wave owns 32 cols x 2 passes.
// Sequential wt->wb lifetimes (no spill); y0 exchanged via shuffles (no LDS).
// ---------------------------------------------------------------------------
#define AR2(q, p) ((((q) * 8) + (p)) * 264)

__global__ __launch_bounds__(512, 4) void metapath_kernel(
    const int* __restrict__ tokens, const int* __restrict__ etok,
    const bf16* __restrict__ scaled_emb, const bf16* __restrict__ WtopT,
    const bf16* __restrict__ WbotT, const float* __restrict__ attn_b,
    const float* __restrict__ ctx, const float* __restrict__ ce,
    const float* __restrict__ se, float* __restrict__ hid) {
    extern __shared__ char smem[];
    bf16* Al = (bf16*)smem;                   // 64*264*2 = 33792
    bf16* h0l = (bf16*)(smem + 33792);        // 8*264*2  =  4224
    float* lg2 = (float*)(smem + 38016);      // 64*9*4   =  2304
    float* wsm = (float*)(smem + 40320);      // 64*4     -> total 40576
    const int tid = threadIdx.x;
    const int m = blockIdx.y, bg = blockIdx.x;  // bg: group of 2 b's
    const int w = tid >> 6, l = tid & 63, lr = l & 15, g = l >> 4;

    for (int i = tid; i < 576; i += 512) lg2[i] = 0.f;

    // 1. gather: 64 rows (8q x 8p) x 32 chunks of 16B
    for (int it = 0; it < 4; ++it) {
        int i = tid + it * 512;
        int row = i >> 5, s = i & 31;
        int q = row >> 3, p = row & 7;
        int a = q >> 1, b = bg * 2 + (q & 1);
        int v = tokens[(((m * AA + a) * BB + b) << 3) + p];
        bf16x8 x = *(const bf16x8*)(scaled_emb + (size_t)v * 256 + s * 8);
        *(bf16x8*)(Al + row * 264 + s * 8) = x;
        if (p == 0) *(bf16x8*)(h0l + q * 264 + s * 8) = x;
    }
    __syncthreads();

    // 2. rotational scan, c-pairs packed in b32
    {
        int q = tid >> 6, cp = tid & 63;
        int c0 = cp * 2;
        int a = q >> 1, b = bg * 2 + (q & 1);
        const int* eb = etok + ((m * AA + a) * BB + b) * LL;
        unsigned ur = *(const unsigned*)(Al + AR2(q, 0) + c0);
        unsigned ui = *(const unsigned*)(Al + AR2(q, 0) + c0 + 128);
        float Sr0 = bf2f(ur & 0xffffu), Sr1 = bf2f(ur >> 16);
        float Si0 = bf2f(ui & 0xffffu), Si1 = bf2f(ui >> 16);
        float P0r = 1.f, P0i = 0.f, P1r = 1.f, P1i = 0.f;
#pragma unroll
        for (int k = 1; k <= LL; ++k) {
            int e = eb[k - 1];
            float2 crv = *(const float2*)(ce + e * 128 + c0);
            float2 civ = *(const float2*)(se + e * 128 + c0);
            float t0r = P0r * crv.x - P0i * civ.x, t0i = P0r * civ.x + P0i * crv.x;
            float t1r = P1r * crv.y - P1i * civ.y, t1i = P1r * civ.y + P1i * crv.y;
            P0r = t0r; P0i = t0i; P1r = t1r; P1i = t1i;
            unsigned xr = *(const unsigned*)(Al + AR2(q, k) + c0);
            unsigned xi = *(const unsigned*)(Al + AR2(q, k) + c0 + 128);
            float xr0 = bf2f(xr & 0xffffu), xr1 = bf2f(xr >> 16);
            float xi0 = bf2f(xi & 0xffffu), xi1 = bf2f(xi >> 16);
            Sr0 += P0r * xr0 - P0i * xi0; Si0 += P0r * xi0 + P0i * xr0;
            Sr1 += P1r * xr1 - P1i * xi1; Si1 += P1r * xi1 + P1i * xr1;
            float inv = 1.f / (float)(k + 1);
            *(unsigned*)(Al + AR2(q, k) + c0) = f2bf(Sr0 * inv) | (f2bf(Sr1 * inv) << 16);
            *(unsigned*)(Al + AR2(q, k) + c0 + 128) = f2bf(Si0 * inv) | (f2bf(Si1 * inv) << 16);
        }
    }
    __syncthreads();

    // 3. attn GEMM, two col-passes; pv accumulates across passes
    const int b_sel = g >> 1;  // q = 2*rt + b_sel for this lane's rows
    float pv[4][4] = {};
    for (int cc = 0; cc < 2; ++cc) {
        const int cb = cc * 256 + w * 32;
        // --- y0: Wtop in regs (lifetime ends inside this scope) ---
        float y0sel[4][2];
        {
            bf16x8 wt[8][2];
#pragma unroll
            for (int ks = 0; ks < 8; ++ks)
#pragma unroll
                for (int ct = 0; ct < 2; ++ct)
                    wt[ks][ct] = *(const bf16x8*)(WtopT + (size_t)(cb + ct * 16 + lr) * 256 +
                                                  ks * 32 + g * 8);
            f32x4 a0[2] = {};
#pragma unroll
            for (int ks = 0; ks < 8; ++ks) {
                bf16x8 aF = *(const bf16x8*)(h0l + (lr & 7) * 264 + ks * 32 + g * 8);
                a0[0] = MFMA16(aF, wt[ks][0], a0[0]);
                a0[1] = MFMA16(aF, wt[ks][1], a0[1]);
            }
            // broadcast y0[q][lane's col] from producer lanes (g'=q>>2, same lr)
#pragma unroll
            for (int rt = 0; rt < 4; ++rt)
#pragma unroll
                for (int ct = 0; ct < 2; ++ct) {
                    float t0 = __shfl(a0[ct][(2 * rt) & 3], (((2 * rt) >> 2) << 4) + lr, 64);
                    float t1 = __shfl(a0[ct][(2 * rt + 1) & 3], (((2 * rt + 1) >> 2) << 4) + lr, 64);
                    y0sel[rt][ct] = b_sel ? t1 : t0;
                }
        }
        // --- Y1: Wbot in regs ---
        bf16x8 wb[8][2];
#pragma unroll
        for (int ks = 0; ks < 8; ++ks)
#pragma unroll
            for (int ct = 0; ct < 2; ++ct)
                wb[ks][ct] = *(const bf16x8*)(WbotT + (size_t)(cb + ct * 16 + lr) * 256 +
                                              ks * 32 + g * 8);
        float bia[2], cxv[2];
#pragma unroll
        for (int ct = 0; ct < 2; ++ct) {
            bia[ct] = attn_b[cb + ct * 16 + lr];
            cxv[ct] = ctx[cb + ct * 16 + lr];
        }
#pragma unroll
        for (int rt = 0; rt < 4; ++rt) {
            f32x4 acc[2] = {};
            __builtin_amdgcn_s_setprio(1);
#pragma unroll
            for (int ks = 0; ks < 8; ++ks) {
                bf16x8 aF = *(const bf16x8*)(Al + (rt * 16 + lr) * 264 + ks * 32 + g * 8);
                acc[0] = MFMA16(aF, wb[ks][0], acc[0]);
                acc[1] = MFMA16(aF, wb[ks][1], acc[1]);
            }
            __builtin_amdgcn_s_setprio(0);
#pragma unroll
            for (int i2 = 0; i2 < 4; ++i2) {
                pv[rt][i2] += cxv[0] * ftanh(acc[0][i2] + y0sel[rt][0] + bia[0]) +
                              cxv[1] * ftanh(acc[1][i2] + y0sel[rt][1] + bia[1]);
            }
        }
    }
    // single lr-reduction of pv, then plain stores (no atomics)
#pragma unroll
    for (int msk = 1; msk < 16; msk <<= 1)
#pragma unroll
        for (int rt = 0; rt < 4; ++rt)
#pragma unroll
            for (int i2 = 0; i2 < 4; ++i2) pv[rt][i2] += __shfl_xor(pv[rt][i2], msk, 64);
    if (lr == 0) {
#pragma unroll
        for (int rt = 0; rt < 4; ++rt)
#pragma unroll
            for (int i2 = 0; i2 < 4; ++i2) {
                int row = rt * 16 + g * 4 + i2;
                if (row & 7) lg2[row * 9 + w] = pv[rt][i2];
            }
    }
    __syncthreads();

    // 4. softmax over 7 positions per q (reduce 8 wave partials inline)
    if (tid < 8) {
        int q = tid;
        float lv[LL], mx = -1e30f;
#pragma unroll
        for (int j = 1; j <= LL; ++j) {
            float sv = 0.f;
#pragma unroll
            for (int w8 = 0; w8 < 8; ++w8) sv += lg2[(q * 8 + j) * 9 + w8];
            lv[j - 1] = sv;
            mx = fmaxf(mx, sv);
        }
        float ssum = 0.f, ev[LL];
#pragma unroll
        for (int j = 0; j < LL; ++j) { ev[j] = __expf(lv[j] - mx); ssum += ev[j]; }
        float inv = 1.f / ssum;
#pragma unroll
        for (int j = 0; j < LL; ++j) wsm[q * 8 + j + 1] = ev[j] * inv;
    }
    __syncthreads();

    // 5. weighted sum + relu + A-reduce -> hid  (c-pairs, 1 per thread)
    {
        int bi = tid >> 8, cp = tid & 255;
        int c0 = cp * 2;
        float acc0 = 0.f, acc1 = 0.f;
        if (c0 < 256) {
#pragma unroll
            for (int a = 0; a < AA; ++a) {
                int q = a * 2 + bi;
                unsigned u = *(const unsigned*)(Al + AR2(q, 0) + c0);
                acc0 += fmaxf(0.f, bf2f(u & 0xffffu));
                acc1 += fmaxf(0.f, bf2f(u >> 16));
            }
        } else {
            int cb2 = c0 - 256;
#pragma unroll
            for (int a = 0; a < AA; ++a) {
                int q = a * 2 + bi;
                float s0 = 0.f, s1 = 0.f;
#pragma unroll
                for (int j = 1; j <= LL; ++j) {
                    unsigned u = *(const unsigned*)(Al + AR2(q, j) + cb2);
                    float wj = wsm[q * 8 + j];
                    s0 += wj * bf2f(u & 0xffffu);
                    s1 += wj * bf2f(u >> 16);
                }
                acc0 += fmaxf(0.f, s0);
                acc1 += fmaxf(0.f, s1);
            }
        }
        float2 o; o.x = acc0; o.y = acc1;
        *(float2*)(hid + ((size_t)(bg * 2 + bi) * 3 + m) * 512 + c0) = o;
    }
}

// ---------------------------------------------------------------------------
// K4a: S[m][c] += sum_b tanh(hid[b][m] . inter_W[:,c] + inter_b[c])
// ---------------------------------------------------------------------------
__global__ __launch_bounds__(1024, 4) void inter_kernel(
    const float* __restrict__ hid, const bf16* __restrict__ inter_WT,
    const float* __restrict__ inter_b, float* __restrict__ S) {
    extern __shared__ char smem[];
    bf16* Al = (bf16*)smem;  // [32][520] = 33280 B
    const int tid = threadIdx.x;
    const int m = blockIdx.y, rb = blockIdx.x * 32;
    const int w = tid >> 6, l = tid & 63, lr = l & 15, g = l >> 4;
    for (int it = 0; it < 4; ++it) {
        int i = tid + it * 1024;
        int r = i >> 7, kq = i & 127;
        float4 x = *(const float4*)(hid + ((size_t)(rb + r) * 3 + m) * 512 + kq * 4);
        bf16* d = Al + r * 520 + kq * 4;
        d[0] = (bf16)x.x; d[1] = (bf16)x.y; d[2] = (bf16)x.z; d[3] = (bf16)x.w;
    }
    __syncthreads();
    for (int cc = 0; cc < 2; ++cc) {
        int c = cc * 256 + w * 16 + lr;
        bf16x8 wf[16];
#pragma unroll
        for (int ks = 0; ks < 16; ++ks)
            wf[ks] = *(const bf16x8*)(inter_WT + (size_t)c * 512 + ks * 32 + g * 8);
        float biav = inter_b[c];
        float csum = 0.f;
        for (int rt = 0; rt < 2; ++rt) {
            f32x4 acc = {};
#pragma unroll
            for (int ks = 0; ks < 16; ++ks) {
                bf16x8 aF = *(const bf16x8*)(Al + (rt * 16 + lr) * 520 + ks * 32 + g * 8);
                acc = MFMA16(aF, wf[ks], acc);
            }
#pragma unroll
            for (int i2 = 0; i2 < 4; ++i2) csum += ftanh(acc[i2] + biav);
        }
        csum += __shfl_xor(csum, 16, 64);
        csum += __shfl_xor(csum, 32, 64);
        if (g == 0) atomicAdd(&S[m * 512 + c], csum);
    }
}

// ---------------------------------------------------------------------------
// K4b: scores[m] = (sum_c S[m][c] * inter_context[c]) / 2048
// ---------------------------------------------------------------------------
__global__ void scores_kernel(const float* __restrict__ S, const float* __restrict__ ictx2,
                              float* __restrict__ scores) {
    __shared__ float red[512];
    int t = threadIdx.x;
    for (int m = 0; m < 3; ++m) {
        red[t] = S[m * 512 + t] * ictx2[t];
        __syncthreads();
        for (int st = 256; st > 0; st >>= 1) {
            if (t < st) red[t] += red[t + st];
            __syncthreads();
        }
        if (t == 0) scores[m] = red[0] * (1.f / 2048.f);
        __syncthreads();
    }
}

// ---------------------------------------------------------------------------
// K4c: out[b] = (sum_m hid[b][m] * scores[m]) @ out_W + out_b
// ---------------------------------------------------------------------------
__global__ __launch_bounds__(1024, 4) void out_kernel(
    const float* __restrict__ hid, const float* __restrict__ scores,
    const bf16* __restrict__ out_WT, const float* __restrict__ out_b,
    float* __restrict__ out) {
    extern __shared__ char smem[];
    bf16* Al = (bf16*)smem;  // [32][520] = 33280 B
    const int tid = threadIdx.x;
    const int rb = blockIdx.x * 32;
    const int w = tid >> 6, l = tid & 63, lr = l & 15, g = l >> 4;
    float s0 = scores[0], s1 = scores[1], s2 = scores[2];
    for (int it = 0; it < 4; ++it) {
        int i = tid + it * 1024;
        int r = i >> 7, kq = i & 127;
        const float* hp = hid + (size_t)(rb + r) * 1536 + kq * 4;
        float4 x0 = *(const float4*)(hp);
        float4 x1 = *(const float4*)(hp + 512);
        float4 x2 = *(const float4*)(hp + 1024);
        bf16* d = Al + r * 520 + kq * 4;
        d[0] = (bf16)(x0.x * s0 + x1.x * s1 + x2.x * s2);
        d[1] = (bf16)(x0.y * s0 + x1.y * s1 + x2.y * s2);
        d[2] = (bf16)(x0.z * s0 + x1.z * s1 + x2.z * s2);
        d[3] = (bf16)(x0.w * s0 + x1.w * s1 + x2.w * s2);
    }
    __syncthreads();
    int c = w * 16 + lr;
    bf16x8 wf[16];
#pragma unroll
    for (int ks = 0; ks < 16; ++ks)
        wf[ks] = *(const bf16x8*)(out_WT + (size_t)c * 512 + ks * 32 + g * 8);
    float biav = out_b[c];
    for (int rt = 0; rt < 2; ++rt) {
        f32x4 acc = {};
#pragma unroll
        for (int ks = 0; ks < 16; ++ks) {
            bf16x8 aF = *(const bf16x8*)(Al + (rt * 16 + lr) * 520 + ks * 32 + g * 8);
            acc = MFMA16(aF, wf[ks], acc);
        }
#pragma unroll
        for (int i2 = 0; i2 < 4; ++i2)
            out[(size_t)(rb + rt * 16 + g * 4 + i2) * 256 + c] = acc[i2] + biav;
    }
}

// ---------------------------------------------------------------------------
extern "C" void kernel_launch(void* const* d_in, const int* in_sizes, int n_in,
                              void* d_out, int out_size, void* d_ws, size_t ws_size,
                              hipStream_t stream) {
    const int* tokens = (const int*)d_in[0];
    const int* etok = (const int*)d_in[1];
    const float* node_emb = (const float*)d_in[2];
    const float* edge_emb = (const float*)d_in[3];
    const float* scale_W = (const float*)d_in[4];
    const float* scale_b = (const float*)d_in[5];
    const float* attn_W = (const float*)d_in[6];
    const float* attn_b = (const float*)d_in[7];
    const float* ictx = (const float*)d_in[8];
    const float* inter_W = (const float*)d_in[9];
    const float* inter_b = (const float*)d_in[10];
    const float* ictx2 = (const float*)d_in[11];
    const float* out_W = (const float*)d_in[12];
    const float* out_b = (const float*)d_in[13];
    float* out = (float*)d_out;
    char* ws = (char*)d_ws;

    // ws layout (bytes) — total identical to proven 39.65 MB budget
    size_t off = 0;
    bf16* scale_WT = (bf16*)(ws + off); off += 256 * 256 * 2;            // 131072
    bf16* WtopT = (bf16*)(ws + off);    off += 512 * 256 * 2;            // 262144
    bf16* WbotT = (bf16*)(ws + off);    off += 512 * 256 * 2;            // 262144
    bf16* inter_WT = (bf16*)(ws + off); off += 512 * 512 * 2;            // 524288
    bf16* out_WT = (bf16*)(ws + off);   off += 512 * 256 * 2;            // 262144
    float* ce = (float*)(ws + off);     off += 16 * 128 * 4;             // 8192
    float* se = (float*)(ws + off);     off += 16 * 128 * 4;             // 8192
    float* S = (float*)(ws + off);      off += 3 * 512 * 4;              // 6144
    float* scores = (float*)(ws + off); off += 256;
    bf16* scaled_emb = (bf16*)(ws + off); off += (size_t)VN * 256 * 2;   // 25.6 MB
    float* hid = (float*)(ws + off);    off += (size_t)BB * 3 * 512 * 4; // 12.6 MB
    if (ws_size < off) return;  // insufficient scratch -> fail loudly (zeros)

    const int lds_k1 = 64 * 264 * 2;   // 33792
    const int lds_k3 = 40576;          // Al+h0l+lg2+wsm
    const int lds_k4 = 32 * 520 * 2;   // 33280

    prep_kernel<<<1024, 256, 0, stream>>>(scale_W, attn_W, inter_W, out_W, edge_emb,
                                          scale_WT, WtopT, WbotT, inter_WT, out_WT, ce, se, S);
    emb_gemm_kernel<<<(VN + 63) / 64, 512, lds_k1, stream>>>(node_emb, scale_WT, scale_b,
                                                             scaled_emb);
    metapath_kernel<<<dim3(BB / 2, MM), 512, lds_k3, stream>>>(tokens, etok, scaled_emb,
                                                               WtopT, WbotT, attn_b, ictx,
                                                               ce, se, hid);
    inter_kernel<<<dim3(BB / 32, MM), 1024, lds_k4, stream>>>(hid, inter_WT, inter_b, S);
    scores_kernel<<<1, 512, 0, stream>>>(S, ictx2, scores);
    out_kernel<<<BB / 32, 1024, lds_k4, stream>>>(hid, scores, out_WT, out_b, out);
}